// Round 3
// baseline (153.925 us; speedup 1.0000x reference)
//
#include <hip/hip_runtime.h>
#include <hip/hip_cooperative_groups.h>

namespace cg = cooperative_groups;

// Problem constants
#define BB 4
#define LL 512
#define WW 256
#define EE 300
#define HH 768

typedef __attribute__((ext_vector_type(8))) short bf16x8;
typedef __attribute__((ext_vector_type(4))) float f32x4;

__device__ __forceinline__ short f2bf(float f) {
    union { float f; unsigned u; } v; v.f = f;
    unsigned r = (v.u + 0x7FFFu + ((v.u >> 16) & 1u)) >> 16;
    return (short)r;
}

// ---------------------------------------------------------------------------
// One cooperative kernel, 256 blocks x 256 threads, 3 phases:
//  P1 (blocks 0..191): a_g = emb_a[word_seq] @ lin_w + lin_b  (bf16, to ws)
//     64m x 64n tile per block, LDS-staged both operands (R1-verified body).
//  -- all blocks also pre-stage their P2 hidden tile (independent of P1) --
//  grid.sync()
//  P2 (all 256): block = (b, 16 l-rows, half of w). u = hid @ a^T via MFMA,
//     double-buffered a-chunk staging (1 barrier/k-step), exp + label-bucket
//     sums -> s_part[row][half*5+c] in ws.
//  grid.sync()
//  P3 (all 256): 8 rows each: o = (sum_c s_c*emb_c[c]) / (sum+1e-10).
// ---------------------------------------------------------------------------
__global__ __launch_bounds__(256) void fused_gca(
    const int*   __restrict__ word_seq,
    const float* __restrict__ hidden,
    const int*   __restrict__ label,
    const float* __restrict__ emb_a,
    const float* __restrict__ lin_w,
    const float* __restrict__ lin_b,
    const float* __restrict__ emb_c,
    float*       __restrict__ out,
    short*       __restrict__ a_g,     // ws: [1024][768] bf16
    float*       __restrict__ s_part)  // ws: [2048][10] f32
{
    __shared__ short ea[64 * 40];        // P1 A tile
    __shared__ short lw[64 * 40];        // P1 B tile
    __shared__ int   word[64];
    __shared__ short hid[16 * 776];      // P2 hidden tile (padded)
    __shared__ short at2[2][128 * 72];   // P2 a-chunk double buffer (padded)
    __shared__ float s_lds[4][16][5];

    cg::grid_group grid = cg::this_grid();

    const int bid = blockIdx.x;
    const int t   = threadIdx.x;
    const int lane = t & 63, wv = t >> 6;
    const int l15 = lane & 15, l4 = lane >> 4;

    // ================= Phase 1: a GEMM (192 blocks) =================
    if (bid < 192) {
        const int m0 = (bid & 15) * 64;
        const int n0 = (bid >> 4) * 64;

        if (t < 64) word[t] = word_seq[m0 + t];
        __syncthreads();

        const int r_ea  = t >> 2;          // 0..63 m-row
        const int ec    = (t & 3) * 8;     // k-chunk
        const int h_lw  = t & 63;          // n-row
        const int kc_lw = (t >> 6) * 8;

        f32x4 acc[4] = {};

        for (int e0 = 0; e0 < 320; e0 += 32) {
            {   // stage ea [64][32]
                const long base = (long)word[r_ea] * EE + e0 + ec;
                float vals[8];
#pragma unroll
                for (int j = 0; j < 8; j += 2) {
                    const int e = e0 + ec + j;
                    if (e < EE) {
                        const float2 p = *(const float2*)(emb_a + base + j);
                        vals[j] = p.x; vals[j + 1] = p.y;
                    } else { vals[j] = 0.f; vals[j + 1] = 0.f; }
                }
                bf16x8 sv;
#pragma unroll
                for (int j = 0; j < 8; ++j) sv[j] = f2bf(vals[j]);
                *(bf16x8*)(&ea[r_ea * 40 + ec]) = sv;
            }
            {   // stage lin_w tile transposed -> [h][k]
                bf16x8 sv;
#pragma unroll
                for (int j = 0; j < 8; ++j) {
                    const int e = e0 + kc_lw + j;
                    sv[j] = (e < EE) ? f2bf(lin_w[(long)e * HH + n0 + h_lw]) : (short)0;
                }
                *(bf16x8*)(&lw[h_lw * 40 + kc_lw]) = sv;
            }
            __syncthreads();
            {
                const bf16x8 af = *(const bf16x8*)(&ea[(wv * 16 + l15) * 40 + l4 * 8]);
#pragma unroll
                for (int nf = 0; nf < 4; ++nf) {
                    const bf16x8 bfv = *(const bf16x8*)(&lw[(nf * 16 + l15) * 40 + l4 * 8]);
                    acc[nf] = __builtin_amdgcn_mfma_f32_16x16x32_bf16(af, bfv, acc[nf], 0, 0, 0);
                }
            }
            __syncthreads();
        }
        // epilogue: bias + bf16 store. D: col = l&15, row = (l>>4)*4 + i
#pragma unroll
        for (int nf = 0; nf < 4; ++nf) {
            const int h    = n0 + nf * 16 + l15;
            const float bv = lin_b[h];
#pragma unroll
            for (int i = 0; i < 4; ++i) {
                const int m = m0 + wv * 16 + l4 * 4 + i;
                a_g[(long)m * HH + h] = f2bf(acc[nf][i] + bv);
            }
        }
    }

    // ---- pre-stage P2 hidden tile (independent of P1 output) ----
    const int blt   = bid >> 1;            // 0..127 : (b*512+l)/16
    const int whalf = bid & 1;
    const int bl0   = blt * 16;
    const int b     = bl0 >> 9;
    const int w0    = whalf * 128;
    {
        const float* hrow = hidden + (long)bl0 * HH;
#pragma unroll
        for (int j = 0; j < 6; ++j) {
            const int idx = (t + j * 256) * 8;      // < 12288, 8 | 768
            const int row = idx / HH;
            const int col = idx - row * HH;
            const float4 p0 = *(const float4*)(hrow + idx);
            const float4 p1 = *(const float4*)(hrow + idx + 4);
            bf16x8 v;
            v[0] = f2bf(p0.x); v[1] = f2bf(p0.y); v[2] = f2bf(p0.z); v[3] = f2bf(p0.w);
            v[4] = f2bf(p1.x); v[5] = f2bf(p1.y); v[6] = f2bf(p1.z); v[7] = f2bf(p1.w);
            *(bf16x8*)(&hid[row * 776 + col]) = v;
        }
    }

    __threadfence();
    grid.sync();

    // ================= Phase 2: u GEMM + bucket sums =================
    {
        const short* abase = a_g + ((long)b * WW + w0) * HH;
        const int wr = (t >> 3);          // base w-row (stride 32 via p)
        const int cc = (t & 7) * 8;       // h offset within 64-chunk

        bf16x8 rg[4];
#pragma unroll
        for (int p = 0; p < 4; ++p)
            rg[p] = *(const bf16x8*)(abase + (long)(wr + 32 * p) * HH + cc);

        f32x4 acc[2] = {};

        for (int kc = 0; kc < 12; ++kc) {
            const int cur = kc & 1;
#pragma unroll
            for (int p = 0; p < 4; ++p)
                *(bf16x8*)(&at2[cur][(wr + 32 * p) * 72 + cc]) = rg[p];
            __syncthreads();
            if (kc < 11) {
                const int h0n = (kc + 1) * 64;
#pragma unroll
                for (int p = 0; p < 4; ++p)
                    rg[p] = *(const bf16x8*)(abase + (long)(wr + 32 * p) * HH + h0n + cc);
            }
            const int h0 = kc * 64;
#pragma unroll
            for (int ks = 0; ks < 2; ++ks) {
                const bf16x8 af = *(const bf16x8*)(&hid[l15 * 776 + h0 + ks * 32 + l4 * 8]);
#pragma unroll
                for (int nf = 0; nf < 2; ++nf) {
                    const bf16x8 bfv =
                        *(const bf16x8*)(&at2[cur][(wv * 32 + nf * 16 + l15) * 72 + ks * 32 + l4 * 8]);
                    acc[nf] = __builtin_amdgcn_mfma_f32_16x16x32_bf16(af, bfv, acc[nf], 0, 0, 0);
                }
            }
        }

        // exp + masked label-bucket accumulation
        const float inv_temper = 0.03608439182435161f;   // 1/sqrt(768)
        float s_loc[4][5];
#pragma unroll
        for (int i = 0; i < 4; ++i)
#pragma unroll
            for (int c = 0; c < 5; ++c) s_loc[i][c] = 0.f;

        const int* lab_base = label + (long)bl0 * WW;
#pragma unroll
        for (int nf = 0; nf < 2; ++nf) {
            const int w = w0 + wv * 32 + nf * 16 + l15;
#pragma unroll
            for (int i = 0; i < 4; ++i) {
                const int row = l4 * 4 + i;
                const int lv  = lab_base[row * WW + w];
                const float e = __expf(acc[nf][i] * inv_temper);
#pragma unroll
                for (int c = 1; c <= 5; ++c)
                    s_loc[i][c - 1] += (lv == c) ? e : 0.f;
            }
        }
#pragma unroll
        for (int i = 0; i < 4; ++i) {
#pragma unroll
            for (int c = 0; c < 5; ++c) {
                float v = s_loc[i][c];
                v += __shfl_xor(v, 1);
                v += __shfl_xor(v, 2);
                v += __shfl_xor(v, 4);
                v += __shfl_xor(v, 8);
                s_loc[i][c] = v;
            }
        }
        if (l15 == 0) {
#pragma unroll
            for (int i = 0; i < 4; ++i)
#pragma unroll
                for (int c = 0; c < 5; ++c)
                    s_lds[wv][l4 * 4 + i][c] = s_loc[i][c];
        }
        __syncthreads();
        if (t < 16) {
#pragma unroll
            for (int c = 0; c < 5; ++c) {
                const float s = s_lds[0][t][c] + s_lds[1][t][c] +
                                s_lds[2][t][c] + s_lds[3][t][c];
                s_part[(long)(bl0 + t) * 10 + whalf * 5 + c] = s;
            }
        }
    }

    __threadfence();
    grid.sync();

    // ================= Phase 3: fused output =================
    {
        float ecv[3][5];
#pragma unroll
        for (int q = 0; q < 3; ++q)
#pragma unroll
            for (int c = 0; c < 5; ++c)
                ecv[q][c] = emb_c[(c + 1) * HH + t + q * 256];

        const int r0 = bid * 8;
        for (int r = 0; r < 8; ++r) {
            const int row = r0 + r;
            float s[5], den = 1e-10f;
#pragma unroll
            for (int c = 0; c < 5; ++c) {
                s[c] = s_part[(long)row * 10 + c] + s_part[(long)row * 10 + 5 + c];
                den += s[c];
            }
            const float id = 1.0f / den;
            float* orow = out + (long)row * HH;
#pragma unroll
            for (int q = 0; q < 3; ++q) {
                const float v = s[0] * ecv[q][0] + s[1] * ecv[q][1] + s[2] * ecv[q][2] +
                                s[3] * ecv[q][3] + s[4] * ecv[q][4];
                orow[t + q * 256] = v * id;
            }
        }
    }
}

extern "C" void kernel_launch(void* const* d_in, const int* in_sizes, int n_in,
                              void* d_out, int out_size, void* d_ws, size_t ws_size,
                              hipStream_t stream) {
    const int*   word_seq = (const int*)  d_in[0];
    const float* hidden   = (const float*)d_in[1];
    const int*   label    = (const int*)  d_in[2];
    const float* emb_a    = (const float*)d_in[3];
    const float* lin_w    = (const float*)d_in[4];
    const float* lin_b    = (const float*)d_in[5];
    const float* emb_c    = (const float*)d_in[6];
    float* out = (float*)d_out;

    short* a_g    = (short*)d_ws;                            // 1.5 MB
    float* s_part = (float*)((char*)d_ws + (long)1024 * 768 * 2);  // 80 KB

    void* args[] = {(void*)&word_seq, (void*)&hidden, (void*)&label,
                    (void*)&emb_a, (void*)&lin_w, (void*)&lin_b, (void*)&emb_c,
                    (void*)&out, (void*)&a_g, (void*)&s_part};
    hipLaunchCooperativeKernel((void*)fused_gca, dim3(256), dim3(256), args, 0, stream);
}

// Round 4
// 27.387 us; speedup vs baseline: 5.6203x; 5.6203x over previous
//
#include <hip/hip_runtime.h>

// Problem constants
#define BB 4
#define LL 512
#define WW 256
#define EE 300
#define HH 768

typedef __attribute__((ext_vector_type(8))) short bf16x8;
typedef __attribute__((ext_vector_type(4))) float f32x4;

__device__ __forceinline__ short f2bf(float f) {
    union { float f; unsigned u; } v; v.f = f;
    unsigned r = (v.u + 0x7FFFu + ((v.u >> 16) & 1u)) >> 16;
    return (short)r;
}

// ---------------------------------------------------------------------------
// k1: a = emb_a[word_seq] @ lin_w + lin_b, written as aT[b][h/8][w][h%8] bf16
// (k-major fragment layout so k2's MFMA B-fragments are coalesced 16B loads).
// 192 blocks x 256 thr; tile 64m x 64n; K=300 pad 320; double-buffered LDS,
// ONE barrier per k-step (reads of buf(i-1) drain at barrier(i)).
// ---------------------------------------------------------------------------
__global__ __launch_bounds__(256) void k1_a_gemm(
    const int*   __restrict__ word_seq,
    const float* __restrict__ emb_a,
    const float* __restrict__ lin_w,
    const float* __restrict__ lin_b,
    short*       __restrict__ aT)      // [4][96][256][8] bf16
{
    __shared__ short ea[2][64 * 40];
    __shared__ short lw[2][64 * 40];
    __shared__ int   word[64];

    const int t  = threadIdx.x;
    const int m0 = (blockIdx.x & 15) * 64;
    const int n0 = (blockIdx.x >> 4) * 64;

    if (t < 64) word[t] = word_seq[m0 + t];
    __syncthreads();

    const int lane = t & 63, wv = t >> 6;
    const int l15 = lane & 15, l4 = lane >> 4;

    const int r_ea  = t >> 2;          // 0..63 m-row
    const int ec    = (t & 3) * 8;     // k-chunk within 32
    const int h_lw  = t & 63;          // n-row
    const int kc_lw = (t >> 6) * 8;    // k-chunk within 32

    const long ea_base = (long)word[r_ea] * EE + ec;

    float ea_reg[8], lw_reg[8];
    // prologue: load k-step 0
    {
#pragma unroll
        for (int j = 0; j < 8; j += 2) {
            const float2 p = *(const float2*)(emb_a + ea_base + j);
            ea_reg[j] = p.x; ea_reg[j + 1] = p.y;
        }
#pragma unroll
        for (int j = 0; j < 8; ++j)
            lw_reg[j] = lin_w[(long)(kc_lw + j) * HH + n0 + h_lw];
    }

    f32x4 acc[4] = {};

#pragma unroll
    for (int it = 0; it < 10; ++it) {
        const int cur = it & 1;
        {   // pack + LDS write
            bf16x8 sv;
#pragma unroll
            for (int j = 0; j < 8; ++j) sv[j] = f2bf(ea_reg[j]);
            *(bf16x8*)(&ea[cur][r_ea * 40 + ec]) = sv;
#pragma unroll
            for (int j = 0; j < 8; ++j) sv[j] = f2bf(lw_reg[j]);
            *(bf16x8*)(&lw[cur][h_lw * 40 + kc_lw]) = sv;
        }
        __syncthreads();
        if (it < 9) {   // prefetch k-step it+1 into regs
            const int e0 = (it + 1) * 32;
#pragma unroll
            for (int j = 0; j < 8; j += 2) {
                const int e = e0 + ec + j;
                if (e < EE) {
                    const float2 p = *(const float2*)(emb_a + ea_base + e0 + j);
                    ea_reg[j] = p.x; ea_reg[j + 1] = p.y;
                } else { ea_reg[j] = 0.f; ea_reg[j + 1] = 0.f; }
            }
#pragma unroll
            for (int j = 0; j < 8; ++j) {
                const int e = e0 + kc_lw + j;
                lw_reg[j] = (e < EE) ? lin_w[(long)e * HH + n0 + h_lw] : 0.f;
            }
        }
        {   // MFMA on buf cur
            const bf16x8 af = *(const bf16x8*)(&ea[cur][(wv * 16 + l15) * 40 + l4 * 8]);
#pragma unroll
            for (int nf = 0; nf < 4; ++nf) {
                const bf16x8 bfv = *(const bf16x8*)(&lw[cur][(nf * 16 + l15) * 40 + l4 * 8]);
                acc[nf] = __builtin_amdgcn_mfma_f32_16x16x32_bf16(af, bfv, acc[nf], 0, 0, 0);
            }
        }
    }

    // epilogue: bias + bf16 store to aT[b][h/8][w][h%8].
    // D frag: col(h) = l15(+nf*16+n0), row(g) = m0 + wv*16 + l4*4 + i
    const int b = m0 >> 8;
#pragma unroll
    for (int nf = 0; nf < 4; ++nf) {
        const int h    = n0 + nf * 16 + l15;
        const float bv = lin_b[h];
        const long hbase = ((long)(b * 96 + (h >> 3)) * 256) * 8 + (h & 7);
#pragma unroll
        for (int i = 0; i < 4; ++i) {
            const int w = (m0 & 255) + wv * 16 + l4 * 4 + i;
            aT[hbase + (long)w * 8] = f2bf(acc[nf][i] + bv);
        }
    }
}

// ---------------------------------------------------------------------------
// k2: per (b, 16 l-rows): u = hid @ a^T, barrier-free fully-unrolled k-loop.
// A-frags from a small hid LDS tile (staged once); B-frags = coalesced 16B
// global loads from aT. Then exp/label-bucket sums + fused output.
// 128 blocks x 256 thr (4 waves; wave wv owns w in [wv*64, wv*64+64)).
// ---------------------------------------------------------------------------
__global__ __launch_bounds__(256) void k2_attn(
    const float* __restrict__ hidden,   // [4][512][768] f32
    const int*   __restrict__ label,    // [4][512][256]
    const short* __restrict__ aT,       // [4][96][256][8] bf16
    const float* __restrict__ emb_c,    // [6][768]
    float*       __restrict__ out)      // [4][512][768]
{
    __shared__ short hid[16 * 776];
    __shared__ float s_lds[4][16][5];
    __shared__ float s_fin[16][5];
    __shared__ float invd[16];

    const int t = threadIdx.x, lane = t & 63, wv = t >> 6;
    const int l15 = lane & 15, l4 = lane >> 4;
    const int bl0 = blockIdx.x * 16;
    const int b   = bl0 >> 9;

    // ---- stage hidden tile -> bf16 LDS (vectorized)
    {
        const float* hrow = hidden + (long)bl0 * HH;
#pragma unroll
        for (int j = 0; j < 6; ++j) {
            const int idx = (t + j * 256) * 8;      // 8 | 768
            const int row = idx / HH;
            const int col = idx - row * HH;
            const float4 p0 = *(const float4*)(hrow + idx);
            const float4 p1 = *(const float4*)(hrow + idx + 4);
            bf16x8 v;
            v[0] = f2bf(p0.x); v[1] = f2bf(p0.y); v[2] = f2bf(p0.z); v[3] = f2bf(p0.w);
            v[4] = f2bf(p1.x); v[5] = f2bf(p1.y); v[6] = f2bf(p1.z); v[7] = f2bf(p1.w);
            *(bf16x8*)(&hid[row * 776 + col]) = v;
        }
    }
    __syncthreads();

    const short* abase = aT + (long)b * 96 * 256 * 8;
    f32x4 acc[4] = {};

#pragma unroll
    for (int ks = 0; ks < 24; ++ks) {
        const bf16x8 af = *(const bf16x8*)(&hid[l15 * 776 + ks * 32 + l4 * 8]);
#pragma unroll
        for (int nf = 0; nf < 4; ++nf) {
            const int w = wv * 64 + nf * 16 + l15;
            const bf16x8 bfv =
                *(const bf16x8*)(abase + ((long)(ks * 4 + l4) * 256 + w) * 8);
            acc[nf] = __builtin_amdgcn_mfma_f32_16x16x32_bf16(af, bfv, acc[nf], 0, 0, 0);
        }
    }

    // ---- exp + masked label-bucket accumulation
    const float inv_temper = 0.03608439182435161f;   // 1/sqrt(768)
    float s_loc[4][5];
#pragma unroll
    for (int i = 0; i < 4; ++i)
#pragma unroll
        for (int c = 0; c < 5; ++c) s_loc[i][c] = 0.f;

    const int* lab_base = label + (long)bl0 * WW;
#pragma unroll
    for (int nf = 0; nf < 4; ++nf) {
        const int w = wv * 64 + nf * 16 + l15;
#pragma unroll
        for (int i = 0; i < 4; ++i) {
            const int row = l4 * 4 + i;
            const int lv  = lab_base[row * WW + w];
            const float e = __expf(acc[nf][i] * inv_temper);
#pragma unroll
            for (int c = 1; c <= 5; ++c)
                s_loc[i][c - 1] += (lv == c) ? e : 0.f;
        }
    }
#pragma unroll
    for (int i = 0; i < 4; ++i) {
#pragma unroll
        for (int c = 0; c < 5; ++c) {
            float v = s_loc[i][c];
            v += __shfl_xor(v, 1);
            v += __shfl_xor(v, 2);
            v += __shfl_xor(v, 4);
            v += __shfl_xor(v, 8);
            s_loc[i][c] = v;
        }
    }
    if (l15 == 0) {
#pragma unroll
        for (int i = 0; i < 4; ++i)
#pragma unroll
            for (int c = 0; c < 5; ++c)
                s_lds[wv][l4 * 4 + i][c] = s_loc[i][c];
    }
    __syncthreads();
    if (t < 16) {
        float den = 0.f;
#pragma unroll
        for (int c = 0; c < 5; ++c) {
            const float s = s_lds[0][t][c] + s_lds[1][t][c] +
                            s_lds[2][t][c] + s_lds[3][t][c];
            s_fin[t][c] = s;
            den += s;
        }
        invd[t] = 1.0f / (den + 1e-10f);
    }
    __syncthreads();

    // ---- fused output: o[row][h] = invd * sum_c s_c * emb_c[c][h]
    float ecv[3][5];
#pragma unroll
    for (int q = 0; q < 3; ++q)
#pragma unroll
        for (int c = 0; c < 5; ++c)
            ecv[q][c] = emb_c[(c + 1) * HH + t + q * 256];

    float* obase = out + (long)bl0 * HH;
    for (int row = 0; row < 16; ++row) {
        const float id = invd[row];
        const float s0 = s_fin[row][0], s1 = s_fin[row][1], s2 = s_fin[row][2],
                    s3 = s_fin[row][3], s4 = s_fin[row][4];
#pragma unroll
        for (int q = 0; q < 3; ++q) {
            const float v = s0 * ecv[q][0] + s1 * ecv[q][1] + s2 * ecv[q][2] +
                            s3 * ecv[q][3] + s4 * ecv[q][4];
            obase[(long)row * HH + t + q * 256] = v * id;
        }
    }
}

extern "C" void kernel_launch(void* const* d_in, const int* in_sizes, int n_in,
                              void* d_out, int out_size, void* d_ws, size_t ws_size,
                              hipStream_t stream) {
    const int*   word_seq = (const int*)  d_in[0];
    const float* hidden   = (const float*)d_in[1];
    const int*   label    = (const int*)  d_in[2];
    const float* emb_a    = (const float*)d_in[3];
    const float* lin_w    = (const float*)d_in[4];
    const float* lin_b    = (const float*)d_in[5];
    const float* emb_c    = (const float*)d_in[6];
    float* out = (float*)d_out;
    short* aT  = (short*)d_ws;   // 4*96*256*8 shorts = 1.5 MB

    k1_a_gemm<<<dim3(192), 256, 0, stream>>>(word_seq, emb_a, lin_w, lin_b, aT);
    k2_attn<<<dim3(128), 256, 0, stream>>>(hidden, label, aT, emb_c, out);
}